// Round 7
// baseline (91.061 us; speedup 1.0000x reference)
//
#include <hip/hip_runtime.h>

// StackedLinear (LSQ-quantized, 8 classes x [32 x 1024]), B=8192.
// out[b,o] = alpha[c,o] * sum_i w_int[c,o,i] * x[b,i] + bias[c,o],  c = idx[b]
// w_int = rint(clip(w/alpha,-128,127)) in [-128,127] -> exact in bf16.
//
// R7: kill the atomic epilogue. One 512-thread block (8 waves) owns one
// 16-sample tile; wave w computes K-chunk w (128 wide); partials reduced
// through LDS; out written once (alpha*acc + bias) -> no atomics, no
// bias-init pass, out-write traffic 9 MB -> 1 MB.
//
// Nodes: 1. prep (64 quant blocks | 8 sort blocks)
//        2. gemm (tile-per-block, 8-wave split-K, LDS reduce, no atomics)

#define IN_F   1024
#define OUT_F  32
#define NCLS   8
#define NB     8192
#define KSPLIT 8
#define KCH    (IN_F / KSPLIT)   // 128
#define GRIDX  68                // tile slots per class; grid-stride covers >68

typedef __attribute__((ext_vector_type(8))) __bf16 bf16x8;
typedef __attribute__((ext_vector_type(4))) float  f32x4;

__device__ __forceinline__ unsigned short f2bf(float f) {
    unsigned int u = __builtin_bit_cast(unsigned int, f);
    u += 0x7FFFu + ((u >> 16) & 1u);
    return (unsigned short)(u >> 16);
}

__device__ __forceinline__ bf16x8 pack8(float4 v0, float4 v1) {
    union { unsigned short u[8]; bf16x8 v; } r;
    r.u[0] = f2bf(v0.x); r.u[1] = f2bf(v0.y); r.u[2] = f2bf(v0.z); r.u[3] = f2bf(v0.w);
    r.u[4] = f2bf(v1.x); r.u[5] = f2bf(v1.y); r.u[6] = f2bf(v1.z); r.u[7] = f2bf(v1.w);
    return r.v;
}

// ---------------------------------------------------------------------------
// Prep, 72 blocks x 1024 threads:
//   blocks 0..63: quantize 4 weight rows each -> bf16 wq + alf
//   blocks 64..71: bucket sort for class (blockIdx.x-64): scalar shuffle
//                  scan over 8 samples/thread, contiguous scatter, counts[c].
//   int64-vs-int32 width detect per block (int64 vals 0..7 => odd words all
//   zero, every block agrees; int32 => P(false) <= 8^-4096 per block).
__global__ __launch_bounds__(1024) void prep_kernel(
    const float* __restrict__ weight, const float* __restrict__ law,
    const unsigned int* __restrict__ lsw,
    float* __restrict__ alf, unsigned short* __restrict__ wq,
    int* __restrict__ counts, unsigned short* __restrict__ buckets)
{
    int t = threadIdx.x;
    if (blockIdx.x < 64) {
        // ---- quantize: 4 rows per block, 256 threads per row (float4 each)
        int row = blockIdx.x * 4 + (t >> 8);
        int c4  = t & 255;
        float a = expf(law[row]);
        if (c4 == 0) alf[row] = a;
        float4 v = ((const float4*)(weight + (size_t)row * IN_F))[c4];
        ushort4 p;
        p.x = f2bf(rintf(fminf(fmaxf(v.x / a, -128.f), 127.f)));
        p.y = f2bf(rintf(fminf(fmaxf(v.y / a, -128.f), 127.f)));
        p.z = f2bf(rintf(fminf(fmaxf(v.z / a, -128.f), 127.f)));
        p.w = f2bf(rintf(fminf(fmaxf(v.w / a, -128.f), 127.f)));
        ((ushort4*)(wq + (size_t)row * IN_F))[c4] = p;
        return;
    }
    // ---- sort block for class c: 1024 threads = 16 waves, 8 samples/thread
    int c = (int)blockIdx.x - 64;
    int lane = t & 63, wv = t >> 6;
    __shared__ int s_is64;
    __shared__ int wtot[16];
    __shared__ int wbase[16];
    if (t == 0) s_is64 = 1;
    __syncthreads();
    int bad = 0;
    #pragma unroll
    for (int j = 0; j < 4; ++j) bad |= (lsw[2 * (j * 1024 + t) + 1] != 0u);
    if (bad) atomicAnd(&s_is64, 0);
    __syncthreads();
    int is64 = s_is64;
    unsigned int match = 0;
    int cnt = 0;
    #pragma unroll
    for (int j = 0; j < 8; ++j) {
        int b = j * 1024 + t;
        int cl = is64 ? (int)lsw[2 * b] : (int)lsw[b];
        if (cl == c) { match |= 1u << j; ++cnt; }
    }
    int inc = cnt;
    #pragma unroll
    for (int d = 1; d < 64; d <<= 1) {
        int o = __shfl_up(inc, d);
        if (lane >= d) inc += o;
    }
    if (lane == 63) wtot[wv] = inc;
    __syncthreads();
    if (t < 16) {
        int b0 = 0;
        for (int w2 = 0; w2 < t; ++w2) b0 += wtot[w2];
        wbase[t] = b0;
        if (t == 15) counts[c] = b0 + wtot[15];
    }
    __syncthreads();
    int pos = wbase[wv] + inc - cnt;
    unsigned short* bk = buckets + c * NB;
    #pragma unroll
    for (int j = 0; j < 8; ++j) {
        if ((match >> j) & 1u) bk[pos++] = (unsigned short)(j * 1024 + t);
    }
}

// ---------------------------------------------------------------------------
// GEMM: block = 512 thr = 8 waves; one 16-sample tile per block iteration.
// Wave w computes K-chunk w (128 wide), both n-halves (2 accs); partials
// reduced via LDS; single non-atomic out write with alpha+bias fused.
// MFMA 16x16x32 bf16 layouts (verified R1-R6): A[m=lane&15][k=q*8+j],
// B^T[n=lane&15][k=q*8+j], D: n=lane&15, m=q*4+reg.
__global__ __launch_bounds__(512) void gemm_kernel(
    const float* __restrict__ x, const float* __restrict__ alf,
    const unsigned short* __restrict__ wq, const float* __restrict__ bias,
    const int* __restrict__ counts, const unsigned short* __restrict__ buckets,
    float* __restrict__ out)
{
    int c = blockIdx.y;
    int cnt = counts[c];
    int ntiles = (cnt + 15) >> 4;
    if ((int)blockIdx.x >= ntiles) return;       // uniform: safe before barriers

    __shared__ float lred[KSPLIT][16][33];       // +1 pad: 2-way (free) reads
    __shared__ int   sid[16];

    int t = threadIdx.x;
    int wv = t >> 6, lane = t & 63;
    int fr = lane & 15, fq = lane >> 4;
    int k0 = wv * KCH;

    // B fragments for this wave's K-chunk, both n-halves (L2-hot)
    const unsigned short* wrow0 = wq + (size_t)(c * OUT_F + fr) * IN_F + k0 + fq * 8;
    const unsigned short* wrow1 = wrow0 + 16 * IN_F;
    bf16x8 Bf0[KCH / 32], Bf1[KCH / 32];
    #pragma unroll
    for (int kk = 0; kk < KCH / 32; ++kk) {
        Bf0[kk] = *(const bf16x8*)(wrow0 + kk * 32);
        Bf1[kk] = *(const bf16x8*)(wrow1 + kk * 32);
    }
    // epilogue constants: thread t owns (m = t>>5, o = t&31)
    int em = t >> 5, eo = t & 31;
    float av = alf[c * OUT_F + eo];
    float bv = bias[c * OUT_F + eo];

    for (int tile = blockIdx.x; tile < ntiles; tile += GRIDX) {
        int start = tile * 16;
        int nvalid = min(16, cnt - start);
        if (t < 16)
            sid[t] = (int)buckets[c * NB + start + min(t, nvalid - 1)];
        __syncthreads();

        int srow = sid[fr];                       // lane's m-row sample id
        const float* xr = x + (size_t)srow * IN_F + k0 + fq * 8;
        f32x4 acc0 = {0.f, 0.f, 0.f, 0.f};
        f32x4 acc1 = {0.f, 0.f, 0.f, 0.f};
        #pragma unroll
        for (int kk = 0; kk < KCH / 32; ++kk) {
            float4 v0 = *(const float4*)(xr + kk * 32);
            float4 v1 = *(const float4*)(xr + kk * 32 + 4);
            bf16x8 a = pack8(v0, v1);
            acc0 = __builtin_amdgcn_mfma_f32_16x16x32_bf16(a, Bf0[kk], acc0, 0, 0, 0);
            acc1 = __builtin_amdgcn_mfma_f32_16x16x32_bf16(a, Bf1[kk], acc1, 0, 0, 0);
        }
        // stash partials: D layout n=lane&15, m=fq*4+reg
        #pragma unroll
        for (int reg = 0; reg < 4; ++reg) {
            int m = fq * 4 + reg;
            lred[wv][m][fr]      = acc0[reg];
            lred[wv][m][16 + fr] = acc1[reg];
        }
        __syncthreads();
        // reduce 8 partials + fused alpha/bias, single coalesced store
        if (em < nvalid) {
            float s = 0.f;
            #pragma unroll
            for (int w2 = 0; w2 < KSPLIT; ++w2) s += lred[w2][em][eo];
            out[(size_t)sid[em] * OUT_F + eo] = s * av + bv;
        }
        __syncthreads();                          // protect sid/lred for next tile
    }
}

// ---------------------------------------------------------------------------
extern "C" void kernel_launch(void* const* d_in, const int* in_sizes, int n_in,
                              void* d_out, int out_size, void* d_ws, size_t ws_size,
                              hipStream_t stream)
{
    (void)in_sizes; (void)n_in; (void)out_size; (void)ws_size;
    const float*        x      = (const float*)d_in[0];
    const unsigned int* ls     = (const unsigned int*)d_in[1];
    const float*        weight = (const float*)d_in[2];
    const float*        bias   = (const float*)d_in[3];
    const float*        law    = (const float*)d_in[4];
    float*              out    = (float*)d_out;

    char* ws = (char*)d_ws;
    int*            counts  = (int*)ws;                                   // 32 B
    float*          alf     = (float*)(ws + 64);                          // 1 KB
    unsigned short* wq      = (unsigned short*)(ws + 64 + 1024);          // 512 KB
    unsigned short* buckets = (unsigned short*)(ws + 64 + 1024 + 524288); // 128 KB

    prep_kernel<<<72, 1024, 0, stream>>>(
        weight, law, ls, alf, wq, counts, buckets);
    gemm_kernel<<<dim3(GRIDX, NCLS), 512, 0, stream>>>(
        x, alf, wq, bias, counts, buckets, out);
}